// Round 1
// baseline (7553.275 us; speedup 1.0000x reference)
//
#include <hip/hip_runtime.h>

// RecurrentGaussianActor: fused LSTM(64->256) + Linear+ReLU(256) + 2 heads(16).
// One WG per batch row (256 WGs), persistent over T=1000 steps.
//
// Round-2 restructuring vs the 512-thread version:
//  * 1024 threads, __launch_bounds__(1024,4): 16 waves/CU (4/SIMD, occupancy
//    ~47%) with a hard 128-VGPR cap -> weights fit in addressable VGPRs
//    (24 x h8 = 96 regs/thread), no AGPR shuffle traffic.
//  * Quad-sliced recurrent dot: thread (u = tid>>2, k = tid&3) computes
//    PARTIAL dots of all 4 gate rows {u,256+u,512+u,768+u} over the h-slice
//    [64k, 64k+64). Only 8 hbuf b128 reads/thread/step (wave64 LDS return is
//    1024B per b128 regardless of broadcast, so this halves the dominant LDS
//    return traffic: ~400KB -> ~263KB per step per CU).
//  * Cross-quad reduce + all-gather via DPP quad_perm butterflies (VALU only):
//    no gbuf LDS round-trip. Double-buffered hbuf -> ONE barrier per step.
//  * xg stored in a thread-private LDS slot (same-thread RAW, no barrier).

#define NB 256
#define NT 1000
#define NF 64
#define NH 256
#define NG 1024
#define NA 16
#define NTHREADS 1024
#define CHUNK 8
#define NCHUNK (NT / CHUNK)

typedef _Float16 h2 __attribute__((ext_vector_type(2)));
typedef _Float16 h8 __attribute__((ext_vector_type(8)));
typedef float f4 __attribute__((ext_vector_type(4)));

__device__ __forceinline__ float fdot2(h2 a, h2 b, float c) {
  return __builtin_amdgcn_fdot2(a, b, c, false);
}
__device__ __forceinline__ float fexp2(float x) { return __builtin_amdgcn_exp2f(x); }
__device__ __forceinline__ float frcp(float x) { return __builtin_amdgcn_rcpf(x); }
__device__ __forceinline__ float sigmoidf_(float x) {
  return frcp(1.f + fexp2(-1.4426950408889634f * x));
}
__device__ __forceinline__ float tanhfast(float x) {
  float a = fabsf(x);
  float e = fexp2(-2.8853900817779268f * a);
  float r = (1.f - e) * frcp(1.f + e);
  return __builtin_copysignf(r, x);
}
// dot of 8 f16 elements held in two h8 vectors (4 chained v_dot2_f32_f16)
__device__ __forceinline__ float dot8(h8 x, h8 w, float acc) {
  acc = fdot2(__builtin_shufflevector(x, x, 0, 1), __builtin_shufflevector(w, w, 0, 1), acc);
  acc = fdot2(__builtin_shufflevector(x, x, 2, 3), __builtin_shufflevector(w, w, 2, 3), acc);
  acc = fdot2(__builtin_shufflevector(x, x, 4, 5), __builtin_shufflevector(w, w, 4, 5), acc);
  acc = fdot2(__builtin_shufflevector(x, x, 6, 7), __builtin_shufflevector(w, w, 6, 7), acc);
  return acc;
}
// quad_perm DPP: CTRL=0xB1 -> lanes (1,0,3,2) [xor1]; 0x4E -> (2,3,0,1) [xor2]
template <int CTRL>
__device__ __forceinline__ float qperm(float x) {
  return __int_as_float(
      __builtin_amdgcn_update_dpp(0, __float_as_int(x), CTRL, 0xF, 0xF, true));
}

// ---- prep: convert/pack weights to f16 pairs in workspace (~790 KB) ----
__global__ void prep_kernel(const float* __restrict__ Wih, const float* __restrict__ Whh,
                            const float* __restrict__ bih, const float* __restrict__ bhh,
                            const float* __restrict__ W2, const float* __restrict__ Wm,
                            const float* __restrict__ Ws,
                            h2* __restrict__ whh, h2* __restrict__ wih,
                            h2* __restrict__ w2w, h2* __restrict__ wmh,
                            float* __restrict__ bg) {
  int i = blockIdx.x * 256 + threadIdx.x;
  if (i < 1024 * 128) {  // W_hh [1024][256] -> [1024][128] pairs
    int j = i >> 7, p = i & 127;
    whh[i] = h2{(_Float16)Whh[j * 256 + 2 * p], (_Float16)Whh[j * 256 + 2 * p + 1]};
  }
  if (i < 1024 * 32) {   // W_ih [1024][64] -> [1024][32] pairs
    int j = i >> 5, p = i & 31;
    wih[i] = h2{(_Float16)Wih[j * 64 + 2 * p], (_Float16)Wih[j * 64 + 2 * p + 1]};
  }
  if (i < 256 * 128) {   // W2 [256][256] -> [256][128] pairs
    int j = i >> 7, p = i & 127;
    w2w[i] = h2{(_Float16)W2[j * 256 + 2 * p], (_Float16)W2[j * 256 + 2 * p + 1]};
  }
  if (i < 32 * 128) {    // Wm rows 0..15, Ws rows 16..31
    int j = i >> 7, p = i & 127;
    float v0, v1;
    if (j < 16) { v0 = Wm[j * 256 + 2 * p]; v1 = Wm[j * 256 + 2 * p + 1]; }
    else        { v0 = Ws[(j - 16) * 256 + 2 * p]; v1 = Ws[(j - 16) * 256 + 2 * p + 1]; }
    wmh[i] = h2{(_Float16)v0, (_Float16)v1};
  }
  if (i < 1024) bg[i] = bih[i] + bhh[i];
}

// ---- main fused persistent kernel: 1 WG per batch row ----
__global__ __launch_bounds__(NTHREADS, 4) void actor_kernel(
    const float* __restrict__ obs,
    const h2* __restrict__ whh, const h2* __restrict__ wih,
    const h2* __restrict__ w2w, const h2* __restrict__ wmh,
    const float* __restrict__ bg, const float* __restrict__ b2,
    const float* __restrict__ bm, const float* __restrict__ bs,
    float* __restrict__ out) {
  // W_hh slice h8s 0..1 of each of the thread's 4 rows: [g*2+s][tid], b128
  __shared__ __align__(16) h8 whh_l[8 * 1024];          // 131072 B
  __shared__ __align__(16) _Float16 xg_l[CHUNK * NTHREADS];  // 16384 B (private slots)
  __shared__ __align__(16) h2 hbuf[2][NH / 2];          // 1024 B  double-buffered h
  __shared__ __align__(16) h2 hch[CHUNK * NH / 2];      // 4096 B  h history
  __shared__ __align__(16) h2 xbuf[CHUNK * NF / 2];     // 1024 B  obs chunk
  __shared__ __align__(16) h2 x2b[CHUNK * NH / 2];      // 4096 B  layer2 out
  // total 157696 B <= 163840

  const int tid = threadIdx.x;
  const int b = blockIdx.x;
  const int u = tid >> 2;   // hidden unit owned by this quad
  const int k = tid & 3;    // gate slot / h-slice index
  const int R = k * 256 + u;  // "own" gate row (for xg + bias injection)

  // ---- register-resident W_hh: h8 slices 2..7 of rows {g*256+u}, slice k ----
  // 24 x h8 = 96 VGPRs. VOLATILE so the compiler cannot rematerialize the
  // loads inside the step loop (round-1 failure mode).
  h8 wreg[24];
  {
    const volatile h8* vw = (const volatile h8*)whh;  // row stride = 32 h8
#pragma unroll
    for (int g = 0; g < 4; g++)
#pragma unroll
      for (int j = 0; j < 6; j++)
        wreg[g * 6 + j] = vw[(g * 256 + u) * 32 + k * 8 + 2 + j];
  }
  // ---- LDS-resident W_hh: h8 slices 0..1 per row, layout [g*2+s][tid] ----
  {
    const h8* whh8 = (const h8*)whh;
#pragma unroll
    for (int g = 0; g < 4; g++)
#pragma unroll
      for (int s = 0; s < 2; s++)
        whh_l[(g * 2 + s) * 1024 + tid] = whh8[(g * 256 + u) * 32 + k * 8 + s];
  }
  if (tid < NH / 2) hbuf[0][tid] = h2{(_Float16)0.f, (_Float16)0.f};
  float c_state = 0.f;  // replicated across the 4 lanes of a quad
  const float biasg = bg[R];
  const float b2v = b2[tid & 255];
  const int oh = tid & 31;
  const float hbv = (oh < NA) ? bm[oh] : bs[oh - NA];
  __syncthreads();

  const float* obs_b = obs + (size_t)b * NT * NF;
  float* out_means = out;
  float* out_stds = out + (size_t)NB * NT * NA;

  for (int ch = 0; ch < NCHUNK; ++ch) {
    const int t0 = ch * CHUNK;

    // ---- stage obs chunk -> f16 pairs in LDS ----
    if (tid < 128) {
      int t = tid >> 4, fq = tid & 15;
      f4 v = *(const f4*)(obs_b + (size_t)(t0 + t) * NF + fq * 4);
      xbuf[t * 32 + fq * 2] = h2{(_Float16)v[0], (_Float16)v[1]};
      xbuf[t * 32 + fq * 2 + 1] = h2{(_Float16)v[2], (_Float16)v[3]};
    }
    __syncthreads();

    // ---- xg = obs @ W_ih^T + (b_ih+b_hh) for own row; private LDS slot,
    //      same-thread RAW -> no barrier needed ----
    {
      float acc[CHUNK];
#pragma unroll
      for (int t = 0; t < CHUNK; t++) acc[t] = biasg;
      const h8* wrow = (const h8*)wih + R * 8;
#pragma unroll
      for (int jh = 0; jh < 4; jh++) {
        h8 w0 = wrow[jh * 2];
        h8 w1 = wrow[jh * 2 + 1];
#pragma unroll
        for (int t = 0; t < CHUNK; t++) {
          h8 x0 = *(const h8*)&xbuf[t * 32 + jh * 8];
          h8 x1 = *(const h8*)&xbuf[t * 32 + jh * 8 + 4];
          acc[t] = dot8(x0, w0, acc[t]);
          acc[t] = dot8(x1, w1, acc[t]);
        }
      }
#pragma unroll
      for (int t = 0; t < CHUNK; t++) xg_l[t * NTHREADS + tid] = (_Float16)acc[t];
    }

    // ---- 8 recurrent LSTM steps, ONE barrier each ----
    for (int t = 0; t < CHUNK; t++) {
      const _Float16* hb = (const _Float16*)hbuf[t & 1] + k * 64;  // my h-slice
      float xgv = (float)xg_l[t * NTHREADS + tid];
      // partial dots of the 4 gate rows over my 64-element h slice;
      // own-row xg injected exactly once (lane k owns gate k).
      float p0 = (k == 0) ? xgv : 0.f;
      float p1 = (k == 1) ? xgv : 0.f;
      float p2 = (k == 2) ? xgv : 0.f;
      float p3 = (k == 3) ? xgv : 0.f;
#pragma unroll
      for (int s = 0; s < 2; s++) {
        h8 hv = *(const h8*)(hb + s * 8);
        p0 = dot8(hv, whh_l[(0 + s) * 1024 + tid], p0);
        p1 = dot8(hv, whh_l[(2 + s) * 1024 + tid], p1);
        p2 = dot8(hv, whh_l[(4 + s) * 1024 + tid], p2);
        p3 = dot8(hv, whh_l[(6 + s) * 1024 + tid], p3);
      }
#pragma unroll
      for (int j = 0; j < 6; j++) {
        h8 hv = *(const h8*)(hb + 16 + j * 8);
        p0 = dot8(hv, wreg[j], p0);
        p1 = dot8(hv, wreg[6 + j], p1);
        p2 = dot8(hv, wreg[12 + j], p2);
        p3 = dot8(hv, wreg[18 + j], p3);
      }
      // quad butterfly reduce (DPP, VALU-only): all 4 lanes end with all 4
      // full gate pre-activations -> replicated gate math, identical c_state.
      p0 += qperm<0xB1>(p0);
      p1 += qperm<0xB1>(p1);
      p2 += qperm<0xB1>(p2);
      p3 += qperm<0xB1>(p3);
      p0 += qperm<0x4E>(p0);
      p1 += qperm<0x4E>(p1);
      p2 += qperm<0x4E>(p2);
      p3 += qperm<0x4E>(p3);
      float gi = sigmoidf_(p0);
      float gf = sigmoidf_(p1);
      float gg = tanhfast(p2);
      float go = sigmoidf_(p3);
      c_state = gf * c_state + gi * gg;
      float hval = go * tanhfast(c_state);
      if (k == 0) {
        _Float16 hh = (_Float16)hval;
        ((_Float16*)hbuf[(t + 1) & 1])[u] = hh;   // publish h(t+1) (other buffer)
        ((_Float16*)hch)[t * NH + u] = hh;        // history for layer2
      }
      __syncthreads();  // h(t+1) visible; hbuf[t&1] free for step t+2's write
    }

    // ---- layer2: x2 = relu(h @ W2^T + b2); 2 timesteps per thread ----
    {
      const int o = tid & 255;
      const int tb = (tid >> 8) * 2;
      float acc0 = b2v, acc1 = b2v;
      const h8* wrow = (const h8*)w2w + o * 32;
#pragma unroll 2
      for (int c = 0; c < 16; c++) {
        h8 w0 = wrow[c * 2];
        h8 w1 = wrow[c * 2 + 1];
        h8 x0 = *(const h8*)&hch[tb * 128 + c * 8];
        h8 x0b = *(const h8*)&hch[tb * 128 + c * 8 + 4];
        h8 x1 = *(const h8*)&hch[(tb + 1) * 128 + c * 8];
        h8 x1b = *(const h8*)&hch[(tb + 1) * 128 + c * 8 + 4];
        acc0 = dot8(x0, w0, acc0);
        acc0 = dot8(x0b, w1, acc0);
        acc1 = dot8(x1, w0, acc1);
        acc1 = dot8(x1b, w1, acc1);
      }
      ((_Float16*)x2b)[tb * NH + o] = (_Float16)fmaxf(acc0, 0.f);
      ((_Float16*)x2b)[(tb + 1) * NH + o] = (_Float16)fmaxf(acc1, 0.f);
    }
    __syncthreads();

    // ---- heads: 32 outputs x 8 timesteps on first 256 threads ----
    if (tid < 256) {
      const int tt = tid >> 5;
      const h8* wrow = (const h8*)wmh + oh * 32;
      float acc = 0.f;
#pragma unroll 2
      for (int c = 0; c < 32; c++) {
        h8 xv = *(const h8*)&x2b[tt * 128 + c * 4];
        acc = dot8(xv, wrow[c], acc);
      }
      acc += hbv;
      const size_t idx = ((size_t)b * NT + (t0 + tt)) * NA + (oh & 15);
      if (oh < NA) {
        out_means[idx] = acc;
      } else {
        float ls = fminf(fmaxf(acc, -20.f), 2.f);
        out_stds[idx] = fexp2(1.4426950408889634f * ls);
      }
    }
    // no trailing barrier: next chunk's first x2b write (its layer2) is
    // separated from these reads by the staging barrier + 8 step barriers.
  }
}

extern "C" void kernel_launch(void* const* d_in, const int* in_sizes, int n_in,
                              void* d_out, int out_size, void* d_ws, size_t ws_size,
                              hipStream_t stream) {
  const float* obs = (const float*)d_in[0];
  const float* Wih = (const float*)d_in[1];
  const float* Whh = (const float*)d_in[2];
  const float* bih = (const float*)d_in[3];
  const float* bhh = (const float*)d_in[4];
  const float* W2 = (const float*)d_in[5];
  const float* b2 = (const float*)d_in[6];
  const float* Wm = (const float*)d_in[7];
  const float* bm = (const float*)d_in[8];
  const float* Ws = (const float*)d_in[9];
  const float* bs = (const float*)d_in[10];

  char* ws = (char*)d_ws;
  h2* whh = (h2*)(ws + 0);            // 512 KB
  h2* wih = (h2*)(ws + 524288);       // 128 KB
  h2* w2w = (h2*)(ws + 655360);       // 128 KB
  h2* wmh = (h2*)(ws + 786432);       // 16 KB
  float* bg = (float*)(ws + 802816);  // 4 KB

  prep_kernel<<<512, 256, 0, stream>>>(Wih, Whh, bih, bhh, W2, Wm, Ws,
                                       whh, wih, w2w, wmh, bg);
  actor_kernel<<<NB, NTHREADS, 0, stream>>>(obs, whh, wih, w2w, wmh, bg, b2, bm,
                                            bs, (float*)d_out);
}